// Round 2
// baseline (210.237 us; speedup 1.0000x reference)
//
#include <hip/hip_runtime.h>

#define NA 2048
#define NT 256

__device__ __forceinline__ float silu_f(float x) { return x / (1.0f + __expf(-x)); }

__device__ __forceinline__ float wave_reduce(float v) {
    #pragma unroll
    for (int off = 32; off > 0; off >>= 1) v += __shfl_down(v, off, 64);
    return v;
}

// ---------------------------------------------------------------------------
// k1: RBF features + both MLPs for atom i = blockIdx.x.
// 2048 blocks x 256 threads. Writes rawq[i], esr[i], pxyzq[i] = (x,y,z,rawq).
// Block 0 also zero-inits the k2 accumulators (poison-safe: re-done every
// replay, ordered before k2 by the kernel boundary).
// ---------------------------------------------------------------------------
__global__ __launch_bounds__(NT) void k1_feat_mlp(
    const float* __restrict__ pos,
    const float* __restrict__ cw1, const float* __restrict__ cb1,
    const float* __restrict__ cw2, const float* __restrict__ cb2,
    const float* __restrict__ cw3, const float* __restrict__ cb3,
    const float* __restrict__ ew1, const float* __restrict__ eb1,
    const float* __restrict__ ew2, const float* __restrict__ eb2,
    const float* __restrict__ ew3, const float* __restrict__ eb3,
    float4* __restrict__ pxyzq, float* __restrict__ rawq, float* __restrict__ esr,
    float* __restrict__ gsum, unsigned* __restrict__ counter)
{
    __shared__ float wsum[4][16];
    __shared__ float sfeat[16];
    __shared__ float sh1[4][64];
    const int i = blockIdx.x;
    const int tid = threadIdx.x, lane = tid & 63, wv = tid >> 6;

    if (i == 0 && tid == 0) {
        gsum[0] = 0.0f; gsum[1] = 0.0f; gsum[2] = 0.0f;
        *counter = 0u;
    }

    const float pix = pos[3*i], piy = pos[3*i+1], piz = pos[3*i+2];

    float acc[16];
    #pragma unroll
    for (int r = 0; r < 16; ++r) acc[r] = 0.0f;

    for (int j = tid; j < NA; j += NT) {
        float dx = pix - pos[3*j], dy = piy - pos[3*j+1], dz = piz - pos[3*j+2];
        float d2 = dx*dx + dy*dy + dz*dz;
        if (d2 > 0.0f && d2 < 25.0f) {
            float d  = sqrtf(d2);
            float sm = 0.5f * (1.0f + __cosf(0.6283185307179586f * d)); // cos(pi*d/5)
            #pragma unroll
            for (int r = 0; r < 16; ++r) {
                float t = d - (0.5f + 0.3f * (float)r);   // centers linspace(0.5,5,16)
                acc[r] += sm * __expf(-t * t * 25.28395061728395f); // 1/(2*eta^2)
            }
        }
    }
    #pragma unroll
    for (int r = 0; r < 16; ++r) {
        float v = wave_reduce(acc[r]);
        if (lane == 0) wsum[wv][r] = v;
    }
    __syncthreads();
    if (tid < 16) sfeat[tid] = wsum[0][tid] + wsum[1][tid] + wsum[2][tid] + wsum[3][tid];
    __syncthreads();

    // Both MLPs: waves 0,1 are the real tasks; waves 2,3 duplicate (keeps the
    // barrier between layer-1 write and layer-2 read non-divergent).
    const int which = wv & 1;   // 0: charge MLP, 1: energy MLP
    const float* w1 = which ? ew1 : cw1;
    const float* b1 = which ? eb1 : cb1;
    const float* w2 = which ? ew2 : cw2;
    const float* b2 = which ? eb2 : cb2;
    const float* w3 = which ? ew3 : cw3;
    const float* b3 = which ? eb3 : cb3;

    float s = b1[lane];
    #pragma unroll
    for (int r = 0; r < 16; ++r) s += sfeat[r] * w1[r * 64 + lane];
    sh1[wv][lane] = silu_f(s);
    __syncthreads();

    float s2 = b2[lane];
    #pragma unroll 8
    for (int k = 0; k < 64; ++k) s2 += sh1[wv][k] * w2[k * 64 + lane];
    float p = silu_f(s2) * w3[lane];
    p = wave_reduce(p);

    if (lane == 0 && wv < 2) {
        float o = p + b3[0];
        if (wv == 0) { rawq[i] = o; pxyzq[i] = make_float4(pix, piy, piz, o); }
        else         { esr[i] = o; }
    }
}

// ---------------------------------------------------------------------------
// k2: pair pass with RAW charges + fused finalize (last-block pattern).
// Per block i: s_i = sum' qr_j/r_ij, t_i = sum' 1/r_ij, then fold
// (qr_i*s_i, qr_i*t_i, t_i) into gsum via device-scope float atomics.
// The last block to finish reduces rawq/esr, computes
//   E = 0.5*(S_qq + 2c*A + c^2*S_11) + E_sr   (B == A by symmetry of r_ij)
// and writes out[0] and charges out[1..NA].
// ---------------------------------------------------------------------------
__global__ __launch_bounds__(NT) void k2_pair_final(
    const float4* __restrict__ pxyzq,
    const float* __restrict__ rawq, const float* __restrict__ esr,
    float* __restrict__ gsum, unsigned* __restrict__ counter,
    float* __restrict__ out)
{
    __shared__ float wred[4][2];
    __shared__ float sc;
    __shared__ int slast;
    const int i = blockIdx.x, tid = threadIdx.x, lane = tid & 63, wv = tid >> 6;
    const float4 pi = pxyzq[i];

    float s = 0.0f, t = 0.0f;
    for (int j = tid; j < NA; j += NT) {
        float4 pj = pxyzq[j];
        float dx = pi.x - pj.x, dy = pi.y - pj.y, dz = pi.z - pj.z;
        float d2 = dx*dx + dy*dy + dz*dz;
        if (j != i) {
            float rinv = rsqrtf(d2);
            t += rinv;
            s += pj.w * rinv;
        }
    }
    s = wave_reduce(s);
    t = wave_reduce(t);
    if (lane == 0) { wred[wv][0] = s; wred[wv][1] = t; }
    __syncthreads();
    if (tid == 0) {
        float si = wred[0][0] + wred[1][0] + wred[2][0] + wred[3][0];
        float ti = wred[0][1] + wred[1][1] + wred[2][1] + wred[3][1];
        float qi = pi.w;
        atomicAdd(&gsum[0], qi * si);   // S_qq
        atomicAdd(&gsum[1], qi * ti);   // A  (== B)
        atomicAdd(&gsum[2], ti);        // S_11
        __threadfence();                // release our contributions
        unsigned old = atomicAdd(counter, 1u);
        slast = (old == (unsigned)(NA - 1)) ? 1 : 0;
    }
    __syncthreads();
    if (!slast) return;

    // ---- last block: finalize ----
    __threadfence();  // acquire side
    float pq = 0.0f, pe = 0.0f;
    for (int a = tid; a < NA; a += NT) { pq += rawq[a]; pe += esr[a]; }
    pq = wave_reduce(pq);
    pe = wave_reduce(pe);
    if (lane == 0) { wred[wv][0] = pq; wred[wv][1] = pe; }
    __syncthreads();
    if (tid == 0) {
        float qs = wred[0][0] + wred[1][0] + wred[2][0] + wred[3][0];
        float es = wred[0][1] + wred[1][1] + wred[2][1] + wred[3][1];
        float Sqq = atomicAdd(&gsum[0], 0.0f);   // coherent read-back
        float Aqt = atomicAdd(&gsum[1], 0.0f);
        float S11 = atomicAdd(&gsum[2], 0.0f);
        float c = -qs * (1.0f / (float)NA);
        sc = c;
        out[0] = 0.5f * (Sqq + 2.0f * c * Aqt + c * c * S11) + es;
    }
    __syncthreads();
    const float c = sc;
    for (int a = tid; a < NA; a += NT) out[1 + a] = rawq[a] + c;
}

extern "C" void kernel_launch(void* const* d_in, const int* in_sizes, int n_in,
                              void* d_out, int out_size, void* d_ws, size_t ws_size,
                              hipStream_t stream) {
    const float* pos = (const float*)d_in[0];
    const float* cw1 = (const float*)d_in[1];
    const float* cb1 = (const float*)d_in[2];
    const float* cw2 = (const float*)d_in[3];
    const float* cb2 = (const float*)d_in[4];
    const float* cw3 = (const float*)d_in[5];
    const float* cb3 = (const float*)d_in[6];
    const float* ew1 = (const float*)d_in[7];
    const float* eb1 = (const float*)d_in[8];
    const float* ew2 = (const float*)d_in[9];
    const float* eb2 = (const float*)d_in[10];
    const float* ew3 = (const float*)d_in[11];
    const float* eb3 = (const float*)d_in[12];
    float* out = (float*)d_out;

    // workspace layout (all written before read within one replay -> poison-safe)
    float4*   pxyzq   = (float4*)d_ws;              // 2048 float4
    float*    rawq    = (float*)(pxyzq + NA);       // 2048
    float*    esr     = rawq + NA;                  // 2048
    float*    gsum    = esr + NA;                   // 3 floats (+1 pad)
    unsigned* counter = (unsigned*)(gsum + 4);      // 1 uint

    k1_feat_mlp<<<NA, NT, 0, stream>>>(pos,
                                       cw1, cb1, cw2, cb2, cw3, cb3,
                                       ew1, eb1, ew2, eb2, ew3, eb3,
                                       pxyzq, rawq, esr, gsum, counter);
    k2_pair_final<<<NA, NT, 0, stream>>>(pxyzq, rawq, esr, gsum, counter, out);
}

// Round 4
// 100.125 us; speedup vs baseline: 2.0997x; 2.0997x over previous
//
#include <hip/hip_runtime.h>

#define NA 2048
#define NT 256
#define QCAP 512   // neighbor-queue capacity; mean count ~17 (Poisson), P(>512) ~ 0

__device__ __forceinline__ float silu_f(float x) { return x / (1.0f + __expf(-x)); }

__device__ __forceinline__ float wave_reduce(float v) {
    #pragma unroll
    for (int off = 32; off > 0; off >>= 1) v += __shfl_down(v, off, 64);
    return v;
}

// ---------------------------------------------------------------------------
// k1: RBF features + both MLPs for atom i = blockIdx.x.
// Compact-then-compute: the 5A-cutoff hits ~0.8% of pairs, so the expensive
// RBF body (sqrt+cos+16*expf) runs on a compacted LDS queue (~17 entries)
// on wave 0 only, instead of inside the divergent scan loop (where 41% of
// wave-iterations paid the full body for ~0.5 active lanes).
// ---------------------------------------------------------------------------
__global__ __launch_bounds__(NT) void k1_feat_mlp(
    const float* __restrict__ pos,
    const float* __restrict__ cw1, const float* __restrict__ cb1,
    const float* __restrict__ cw2, const float* __restrict__ cb2,
    const float* __restrict__ cw3, const float* __restrict__ cb3,
    const float* __restrict__ ew1, const float* __restrict__ eb1,
    const float* __restrict__ ew2, const float* __restrict__ eb2,
    const float* __restrict__ ew3, const float* __restrict__ eb3,
    float4* __restrict__ pxyzq, float* __restrict__ rawq, float* __restrict__ esr)
{
    __shared__ float sfeat[16];
    __shared__ float sh1[4][64];
    __shared__ float qd[QCAP];
    __shared__ int qn;
    const int i = blockIdx.x;
    const int tid = threadIdx.x, lane = tid & 63, wv = tid >> 6;

    if (tid == 0) qn = 0;
    __syncthreads();

    const float pix = pos[3*i], piy = pos[3*i+1], piz = pos[3*i+2];

    // ---- scan: cheap distance test, append hits to LDS queue ----
    #pragma unroll
    for (int jj = 0; jj < NA / NT; ++jj) {
        const int j = tid + jj * NT;
        float dx = pix - pos[3*j], dy = piy - pos[3*j+1], dz = piz - pos[3*j+2];
        float d2 = dx*dx + dy*dy + dz*dz;
        if (d2 > 0.0f && d2 < 25.0f) {
            int k = atomicAdd(&qn, 1);   // LDS-scope atomic: cheap, capture-legal
            if (k < QCAP) qd[k] = d2;
        }
    }
    __syncthreads();

    // ---- process: expensive RBF on compacted entries, wave 0 only ----
    if (wv == 0) {
        const int n = qn < QCAP ? qn : QCAP;
        float acc[16];
        #pragma unroll
        for (int r = 0; r < 16; ++r) acc[r] = 0.0f;
        for (int k = lane; k < n; k += 64) {
            float d  = sqrtf(qd[k]);
            float sm = 0.5f * (1.0f + __cosf(0.6283185307179586f * d)); // cos(pi*d/5)
            #pragma unroll
            for (int r = 0; r < 16; ++r) {
                float t = d - (0.5f + 0.3f * (float)r);   // centers linspace(0.5,5,16)
                acc[r] += sm * __expf(-t * t * 25.28395061728395f); // 1/(2*eta^2)
            }
        }
        #pragma unroll
        for (int r = 0; r < 16; ++r) {
            float v = wave_reduce(acc[r]);
            if (lane == 0) sfeat[r] = v;
        }
    }
    __syncthreads();

    // ---- both MLPs: waves 0,1 real; waves 2,3 duplicate (keeps the barrier
    //      between layer-1 write and layer-2 read non-divergent) ----
    const int which = wv & 1;   // 0: charge MLP, 1: energy MLP
    const float* w1 = which ? ew1 : cw1;
    const float* b1 = which ? eb1 : cb1;
    const float* w2 = which ? ew2 : cw2;
    const float* b2 = which ? eb2 : cb2;
    const float* w3 = which ? ew3 : cw3;
    const float* b3 = which ? eb3 : cb3;

    float s = b1[lane];
    #pragma unroll
    for (int r = 0; r < 16; ++r) s += sfeat[r] * w1[r * 64 + lane];
    sh1[wv][lane] = silu_f(s);
    __syncthreads();

    float s2 = b2[lane];
    #pragma unroll 8
    for (int k = 0; k < 64; ++k) s2 += sh1[wv][k] * w2[k * 64 + lane];
    float p = silu_f(s2) * w3[lane];
    p = wave_reduce(p);

    if (lane == 0 && wv < 2) {
        float o = p + b3[0];
        if (wv == 0) { rawq[i] = o; pxyzq[i] = make_float4(pix, piy, piz, o); }
        else         { esr[i] = o; }
    }
}

// ---------------------------------------------------------------------------
// k2: pair pass with RAW charges. s_i = sum' qr_j/r_ij, t_i = sum' 1/r_ij.
// One block per atom, coalesced float4 loads (L2-resident), no LDS staging.
// ---------------------------------------------------------------------------
__global__ __launch_bounds__(NT) void k2_pair(const float4* __restrict__ pxyzq,
                                              float* __restrict__ sarr,
                                              float* __restrict__ tarr)
{
    __shared__ float ws[4][2];
    const int i = blockIdx.x, tid = threadIdx.x, lane = tid & 63, wv = tid >> 6;
    const float4 pi = pxyzq[i];
    float s = 0.0f, t = 0.0f;
    for (int j = tid; j < NA; j += NT) {
        float4 pj = pxyzq[j];
        float dx = pi.x - pj.x, dy = pi.y - pj.y, dz = pi.z - pj.z;
        float d2 = dx*dx + dy*dy + dz*dz;
        if (j != i) {
            float rinv = rsqrtf(d2);
            t += rinv;
            s += pj.w * rinv;
        }
    }
    s = wave_reduce(s);
    t = wave_reduce(t);
    if (lane == 0) { ws[wv][0] = s; ws[wv][1] = t; }
    __syncthreads();
    if (tid == 0) {
        sarr[i] = ws[0][0] + ws[1][0] + ws[2][0] + ws[3][0];
        tarr[i] = ws[0][1] + ws[1][1] + ws[2][1] + ws[3][1];
    }
}

// ---------------------------------------------------------------------------
// k3: final reduction + correction + outputs.
// E_lr = 0.5*(S_qq + c*(A + B) + c^2*S_11), c = -sum(qr)/N
//   S_qq = sum qr_i s_i, A = sum qr_i t_i, B = sum s_i, S_11 = sum t_i
// ---------------------------------------------------------------------------
__global__ __launch_bounds__(NT) void k3_final(const float* __restrict__ rawq,
                                               const float* __restrict__ esr,
                                               const float* __restrict__ sarr,
                                               const float* __restrict__ tarr,
                                               float* __restrict__ out)
{
    __shared__ float wred[4][6];
    __shared__ float sc;
    const int tid = threadIdx.x, lane = tid & 63, wv = tid >> 6;
    float pq = 0, pe = 0, pqq = 0, pqt = 0, ps = 0, pt = 0;
    for (int i = tid; i < NA; i += NT) {
        float q = rawq[i], s = sarr[i], t = tarr[i];
        pq += q; pe += esr[i]; pqq += q * s; pqt += q * t; ps += s; pt += t;
    }
    pq  = wave_reduce(pq);  pe = wave_reduce(pe);  pqq = wave_reduce(pqq);
    pqt = wave_reduce(pqt); ps = wave_reduce(ps);  pt  = wave_reduce(pt);
    if (lane == 0) {
        wred[wv][0] = pq; wred[wv][1] = pe; wred[wv][2] = pqq;
        wred[wv][3] = pqt; wred[wv][4] = ps; wred[wv][5] = pt;
    }
    __syncthreads();
    if (tid == 0) {
        float q  = wred[0][0] + wred[1][0] + wred[2][0] + wred[3][0];
        float e  = wred[0][1] + wred[1][1] + wred[2][1] + wred[3][1];
        float qq = wred[0][2] + wred[1][2] + wred[2][2] + wred[3][2];
        float qt = wred[0][3] + wred[1][3] + wred[2][3] + wred[3][3];
        float ss = wred[0][4] + wred[1][4] + wred[2][4] + wred[3][4];
        float tt = wred[0][5] + wred[1][5] + wred[2][5] + wred[3][5];
        float c = -q * (1.0f / (float)NA);
        sc = c;
        out[0] = 0.5f * (qq + c * (qt + ss) + c * c * tt) + e;
    }
    __syncthreads();
    const float c = sc;
    for (int i = tid; i < NA; i += NT) out[1 + i] = rawq[i] + c;
}

extern "C" void kernel_launch(void* const* d_in, const int* in_sizes, int n_in,
                              void* d_out, int out_size, void* d_ws, size_t ws_size,
                              hipStream_t stream) {
    const float* pos = (const float*)d_in[0];
    const float* cw1 = (const float*)d_in[1];
    const float* cb1 = (const float*)d_in[2];
    const float* cw2 = (const float*)d_in[3];
    const float* cb2 = (const float*)d_in[4];
    const float* cw3 = (const float*)d_in[5];
    const float* cb3 = (const float*)d_in[6];
    const float* ew1 = (const float*)d_in[7];
    const float* eb1 = (const float*)d_in[8];
    const float* ew2 = (const float*)d_in[9];
    const float* eb2 = (const float*)d_in[10];
    const float* ew3 = (const float*)d_in[11];
    const float* eb3 = (const float*)d_in[12];
    float* out = (float*)d_out;

    // workspace layout (all written before read within one replay -> poison-safe)
    float4* pxyzq = (float4*)d_ws;                  // 2048 float4
    float*  rawq  = (float*)(pxyzq + NA);           // 2048
    float*  esr   = rawq + NA;                      // 2048
    float*  sarr  = esr + NA;                      // 2048
    float*  tarr  = sarr + NA;                      // 2048

    k1_feat_mlp<<<NA, NT, 0, stream>>>(pos,
                                       cw1, cb1, cw2, cb2, cw3, cb3,
                                       ew1, eb1, ew2, eb2, ew3, eb3,
                                       pxyzq, rawq, esr);
    k2_pair<<<NA, NT, 0, stream>>>(pxyzq, sarr, tarr);
    k3_final<<<1, NT, 0, stream>>>(rawq, esr, sarr, tarr, out);
}

// Round 5
// 98.391 us; speedup vs baseline: 2.1368x; 1.0176x over previous
//
#include <hip/hip_runtime.h>

#define NA 2048
#define NT 256
#define QCAP 512   // neighbor-queue capacity; mean count ~17 (Poisson), P(>512) ~ 0

__device__ __forceinline__ float silu_f(float x) { return x / (1.0f + __expf(-x)); }

// butterfly: result valid in ALL lanes (no broadcast needed)
__device__ __forceinline__ float wave_allreduce(float v) {
    #pragma unroll
    for (int off = 32; off > 0; off >>= 1) v += __shfl_xor(v, off, 64);
    return v;
}

__device__ __forceinline__ float wave_reduce(float v) {
    #pragma unroll
    for (int off = 32; off > 0; off >>= 1) v += __shfl_down(v, off, 64);
    return v;
}

// ---------------------------------------------------------------------------
// k1: RBF features + both MLPs for atom i = blockIdx.x.
// Compact-then-compute scan (divergent RBF body runs on a ~17-entry LDS
// queue, not per wave-iteration). After the single queue barrier, waves 0/1
// each process the queue independently and run one MLP each with NO further
// __syncthreads (per-wave LDS scratch; same-wave RAW is ordered by lgkmcnt).
// Waves 2/3 exit after the scan.
// ---------------------------------------------------------------------------
__global__ __launch_bounds__(NT) void k1_feat_mlp(
    const float* __restrict__ pos,
    const float* __restrict__ cw1, const float* __restrict__ cb1,
    const float* __restrict__ cw2, const float* __restrict__ cb2,
    const float* __restrict__ cw3, const float* __restrict__ cb3,
    const float* __restrict__ ew1, const float* __restrict__ eb1,
    const float* __restrict__ ew2, const float* __restrict__ eb2,
    const float* __restrict__ ew3, const float* __restrict__ eb3,
    float4* __restrict__ pxyzq, float* __restrict__ rawq, float* __restrict__ esr)
{
    __shared__ float qd[QCAP];
    __shared__ int qn;
    __shared__ float sh1[2][64];
    const int i = blockIdx.x;
    const int tid = threadIdx.x, lane = tid & 63, wv = tid >> 6;

    if (tid == 0) qn = 0;
    __syncthreads();

    const float pix = pos[3*i], piy = pos[3*i+1], piz = pos[3*i+2];

    // ---- scan: cheap distance test, append hits to LDS queue ----
    #pragma unroll
    for (int jj = 0; jj < NA / NT; ++jj) {
        const int j = tid + jj * NT;
        float dx = pix - pos[3*j], dy = piy - pos[3*j+1], dz = piz - pos[3*j+2];
        float d2 = dx*dx + dy*dy + dz*dz;
        if (d2 > 0.0f && d2 < 25.0f) {
            int k = atomicAdd(&qn, 1);   // LDS-scope atomic: cheap, capture-legal
            if (k < QCAP) qd[k] = d2;
        }
    }
    __syncthreads();   // queue complete — LAST barrier in this kernel

    if (wv >= 2) return;   // waves 2/3 done

    // ---- process: each of waves 0/1 computes features from the queue ----
    const int n = qn < QCAP ? qn : QCAP;
    float acc[16];
    #pragma unroll
    for (int r = 0; r < 16; ++r) acc[r] = 0.0f;
    for (int k = lane; k < n; k += 64) {
        float d  = sqrtf(qd[k]);
        float sm = 0.5f * (1.0f + __cosf(0.6283185307179586f * d)); // cos(pi*d/5)
        #pragma unroll
        for (int r = 0; r < 16; ++r) {
            float t = d - (0.5f + 0.3f * (float)r);   // centers linspace(0.5,5,16)
            acc[r] += sm * __expf(-t * t * 25.28395061728395f); // 1/(2*eta^2)
        }
    }

    // wave 0: charge MLP; wave 1: energy MLP
    const float* w1 = wv ? ew1 : cw1;
    const float* b1 = wv ? eb1 : cb1;
    const float* w2 = wv ? ew2 : cw2;
    const float* b2 = wv ? eb2 : cb2;
    const float* w3 = wv ? ew3 : cw3;
    const float* b3 = wv ? eb3 : cb3;

    // fused feature-allreduce + layer 1 (features land in all lanes)
    float s = b1[lane];
    #pragma unroll
    for (int r = 0; r < 16; ++r) {
        float f = wave_allreduce(acc[r]);
        s += f * w1[r * 64 + lane];
    }
    sh1[wv][lane] = silu_f(s);
    // same-wave LDS RAW: DS ops execute in order per wave; compiler emits the
    // lgkmcnt wait. No __syncthreads needed (per-wave scratch).
    float s2 = b2[lane];
    #pragma unroll 8
    for (int k = 0; k < 64; ++k) s2 += sh1[wv][k] * w2[k * 64 + lane];
    float p = silu_f(s2) * w3[lane];
    p = wave_reduce(p);

    if (lane == 0) {
        float o = p + b3[0];
        if (wv == 0) { rawq[i] = o; pxyzq[i] = make_float4(pix, piy, piz, o); }
        else         { esr[i] = o; }
    }
}

// ---------------------------------------------------------------------------
// k2: pair pass with RAW charges, TWO atoms per block (1024 blocks).
// Each loaded pj serves both i0 and i1 -> halves L2 traffic and block count.
// s_i = sum' qr_j/r_ij, t_i = sum' 1/r_ij.
// ---------------------------------------------------------------------------
__global__ __launch_bounds__(NT) void k2_pair(const float4* __restrict__ pxyzq,
                                              float* __restrict__ sarr,
                                              float* __restrict__ tarr)
{
    __shared__ float ws[4][4];
    const int i0 = blockIdx.x * 2, i1 = i0 + 1;
    const int tid = threadIdx.x, lane = tid & 63, wv = tid >> 6;
    const float4 pa = pxyzq[i0];
    const float4 pb = pxyzq[i1];
    float s0 = 0.0f, t0 = 0.0f, s1 = 0.0f, t1 = 0.0f;
    #pragma unroll
    for (int jj = 0; jj < NA / NT; ++jj) {
        const int j = tid + jj * NT;
        float4 pj = pxyzq[j];
        float dxa = pa.x - pj.x, dya = pa.y - pj.y, dza = pa.z - pj.z;
        float d2a = dxa*dxa + dya*dya + dza*dza;
        if (j != i0) {
            float rinv = rsqrtf(d2a);
            t0 += rinv;
            s0 += pj.w * rinv;
        }
        float dxb = pb.x - pj.x, dyb = pb.y - pj.y, dzb = pb.z - pj.z;
        float d2b = dxb*dxb + dyb*dyb + dzb*dzb;
        if (j != i1) {
            float rinv = rsqrtf(d2b);
            t1 += rinv;
            s1 += pj.w * rinv;
        }
    }
    s0 = wave_reduce(s0); t0 = wave_reduce(t0);
    s1 = wave_reduce(s1); t1 = wave_reduce(t1);
    if (lane == 0) { ws[wv][0] = s0; ws[wv][1] = t0; ws[wv][2] = s1; ws[wv][3] = t1; }
    __syncthreads();
    if (tid == 0) {
        sarr[i0] = ws[0][0] + ws[1][0] + ws[2][0] + ws[3][0];
        tarr[i0] = ws[0][1] + ws[1][1] + ws[2][1] + ws[3][1];
        sarr[i1] = ws[0][2] + ws[1][2] + ws[2][2] + ws[3][2];
        tarr[i1] = ws[0][3] + ws[1][3] + ws[2][3] + ws[3][3];
    }
}

// ---------------------------------------------------------------------------
// k3: final reduction + correction + outputs.
// E_lr = 0.5*(S_qq + c*(A + B) + c^2*S_11), c = -sum(qr)/N
//   S_qq = sum qr_i s_i, A = sum qr_i t_i, B = sum s_i, S_11 = sum t_i
// ---------------------------------------------------------------------------
__global__ __launch_bounds__(NT) void k3_final(const float* __restrict__ rawq,
                                               const float* __restrict__ esr,
                                               const float* __restrict__ sarr,
                                               const float* __restrict__ tarr,
                                               float* __restrict__ out)
{
    __shared__ float wred[4][6];
    __shared__ float sc;
    const int tid = threadIdx.x, lane = tid & 63, wv = tid >> 6;
    float pq = 0, pe = 0, pqq = 0, pqt = 0, ps = 0, pt = 0;
    for (int i = tid; i < NA; i += NT) {
        float q = rawq[i], s = sarr[i], t = tarr[i];
        pq += q; pe += esr[i]; pqq += q * s; pqt += q * t; ps += s; pt += t;
    }
    pq  = wave_reduce(pq);  pe = wave_reduce(pe);  pqq = wave_reduce(pqq);
    pqt = wave_reduce(pqt); ps = wave_reduce(ps);  pt  = wave_reduce(pt);
    if (lane == 0) {
        wred[wv][0] = pq; wred[wv][1] = pe; wred[wv][2] = pqq;
        wred[wv][3] = pqt; wred[wv][4] = ps; wred[wv][5] = pt;
    }
    __syncthreads();
    if (tid == 0) {
        float q  = wred[0][0] + wred[1][0] + wred[2][0] + wred[3][0];
        float e  = wred[0][1] + wred[1][1] + wred[2][1] + wred[3][1];
        float qq = wred[0][2] + wred[1][2] + wred[2][2] + wred[3][2];
        float qt = wred[0][3] + wred[1][3] + wred[2][3] + wred[3][3];
        float ss = wred[0][4] + wred[1][4] + wred[2][4] + wred[3][4];
        float tt = wred[0][5] + wred[1][5] + wred[2][5] + wred[3][5];
        float c = -q * (1.0f / (float)NA);
        sc = c;
        out[0] = 0.5f * (qq + c * (qt + ss) + c * c * tt) + e;
    }
    __syncthreads();
    const float c = sc;
    for (int i = tid; i < NA; i += NT) out[1 + i] = rawq[i] + c;
}

extern "C" void kernel_launch(void* const* d_in, const int* in_sizes, int n_in,
                              void* d_out, int out_size, void* d_ws, size_t ws_size,
                              hipStream_t stream) {
    const float* pos = (const float*)d_in[0];
    const float* cw1 = (const float*)d_in[1];
    const float* cb1 = (const float*)d_in[2];
    const float* cw2 = (const float*)d_in[3];
    const float* cb2 = (const float*)d_in[4];
    const float* cw3 = (const float*)d_in[5];
    const float* cb3 = (const float*)d_in[6];
    const float* ew1 = (const float*)d_in[7];
    const float* eb1 = (const float*)d_in[8];
    const float* ew2 = (const float*)d_in[9];
    const float* eb2 = (const float*)d_in[10];
    const float* ew3 = (const float*)d_in[11];
    const float* eb3 = (const float*)d_in[12];
    float* out = (float*)d_out;

    // workspace layout (all written before read within one replay -> poison-safe)
    float4* pxyzq = (float4*)d_ws;                  // 2048 float4
    float*  rawq  = (float*)(pxyzq + NA);           // 2048
    float*  esr   = rawq + NA;                      // 2048
    float*  sarr  = esr + NA;                       // 2048
    float*  tarr  = sarr + NA;                      // 2048

    k1_feat_mlp<<<NA, NT, 0, stream>>>(pos,
                                       cw1, cb1, cw2, cb2, cw3, cb3,
                                       ew1, eb1, ew2, eb2, ew3, eb3,
                                       pxyzq, rawq, esr);
    k2_pair<<<NA / 2, NT, 0, stream>>>(pxyzq, sarr, tarr);
    k3_final<<<1, NT, 0, stream>>>(rawq, esr, sarr, tarr, out);
}